// Round 11
// baseline (186.058 us; speedup 1.0000x reference)
//
#include <hip/hip_runtime.h>
#include <cstdint>
#include <cstddef>

typedef __bf16 bf16x8 __attribute__((ext_vector_type(8)));
typedef __bf16 bf16x2v __attribute__((ext_vector_type(2)));
typedef unsigned short u16;
typedef u16 u16x8v __attribute__((ext_vector_type(8)));
typedef float  f32x4  __attribute__((ext_vector_type(4)));
typedef unsigned int u32;

#define MFMA16(a, b, c) __builtin_amdgcn_mfma_f32_16x16x32_bf16((a), (b), (c), 0, 0, 0)
#define ASYNC16(g, l)                                                              \
  __builtin_amdgcn_global_load_lds(                                                \
      (const __attribute__((address_space(1))) unsigned int*)(g),                  \
      (__attribute__((address_space(3))) unsigned int*)(l), 16, 0, 0)

__device__ __forceinline__ u16 f2bf(float f) {
  unsigned u = __builtin_bit_cast(unsigned, f);
  u += 0x7fffu + ((u >> 16) & 1u);
  return (u16)(u >> 16);
}

// packed fp32x2 -> bf16x2 (RNE) via hardware cvt
__device__ __forceinline__ u32 cvt2(float a, float b) {
  bf16x2v t;
  t[0] = (__bf16)a;
  t[1] = (__bf16)b;
  return __builtin_bit_cast(u32, t);
}

#define SEQ 2048
#define CH  1024
#define NH  16
#define HD  64
// log2(e) / sqrt(64) folded into stored Q so softmax uses exp2
#define QSCALE 0.18033688011112042f

// ------------- fused prep: cast x + transpose-cast qkv_w + proj_w -------------
// (round-2 original, measured-best)
__global__ void __launch_bounds__(256) prep_kernel(const float* __restrict__ x,
                                                   const float* __restrict__ qkv_w,
                                                   const float* __restrict__ proj_w,
                                                   u16* __restrict__ xb,
                                                   u16* __restrict__ wqkvt,
                                                   u16* __restrict__ wprojt) {
  __shared__ u16 t[64][68];
  int bx = blockIdx.x;
  int tx = threadIdx.x;
  if (bx < 4096) {
    int i = bx * 256 + tx;
    float4 v = ((const float4*)x)[i];
    ushort4 o;
    o.x = f2bf(v.x); o.y = f2bf(v.y); o.z = f2bf(v.z); o.w = f2bf(v.w);
    ((ushort4*)xb)[i] = o;
    return;
  }
  const float* in; u16* out; int R, C, c0, r0;
  if (bx < 4096 + 768) {
    int i = bx - 4096;
    in = qkv_w; out = wqkvt; R = 1024; C = 3072;
    c0 = (i % 48) * 64; r0 = (i / 48) * 64;
  } else {
    int i = bx - 4864;
    in = proj_w; out = wprojt; R = 1024; C = 1024;
    c0 = (i % 16) * 64; r0 = (i / 16) * 64;
  }
  int rr = tx >> 6, cc = tx & 63;
#pragma unroll
  for (int i = 0; i < 16; ++i) {
    int r = i * 4 + rr;
    t[r][cc] = f2bf(in[(size_t)(r0 + r) * C + c0 + cc]);
  }
  __syncthreads();
#pragma unroll
  for (int i = 0; i < 16; ++i) {
    int r = i * 4 + rr;
    out[(size_t)(c0 + r) * R + r0 + cc] = t[cc][r];
  }
}

// ------------- GEMM v4 (round-2 exact, measured-best): BK=64, XOR-swizzled LDS,
//               double-buffered staging, two barriers/iter, coalesced epilogue ----
// Session lessons: XCD swizzle regresses (r3); single-barrier +3us (r4);
// 256²/8-phase neutral (r8); gemm2 MT=4 at (8,32) regresses +6us (r10: 1
// block/CU kills cross-block overlap; 2 co-resident blocks beat per-block
// efficiency). This structure is CLOSED: MT=4 gemm1 (24,32), MT=2 gemm2 (8,64).
template <int MT>
__global__ void __launch_bounds__(256) gemm_kernel(const u16* __restrict__ A,
                                                   const u16* __restrict__ Bt,
                                                   const float* __restrict__ bias,
                                                   u16* __restrict__ qk,
                                                   u16* __restrict__ vtout,
                                                   float* __restrict__ outf,
                                                   int K, int mode) {
  constexpr int R = MT * 32;
  __shared__ alignas(16) u16 smem[2 * R * 64 + 2 * 128 * 64];
  auto As = (u16(*)[R * 64])smem;
  auto Bs = (u16(*)[128 * 64])(smem + 2 * R * 64);
  int tid = threadIdx.x;
  int lane = tid & 63, wave = tid >> 6;
  int wm = wave >> 1, wn = wave & 1;
  int qr = lane & 15, quad = lane >> 4;
  size_t rowA = (size_t)blockIdx.y * R;
  size_t rowB = (size_t)blockIdx.x * 128;

  int klr = lane >> 3;
  int kcs = (lane & 7) ^ klr;

  f32x4 acc[MT][4];
#pragma unroll
  for (int mt = 0; mt < MT; ++mt)
#pragma unroll
    for (int nt = 0; nt < 4; ++nt) acc[mt][nt] = (f32x4){0.f, 0.f, 0.f, 0.f};

  auto stage = [&](int buf, int k0) {
#pragma unroll
    for (int i = 0; i < R / 32; ++i) {
      int ar = wave * (R / 4) + i * 8;
      ASYNC16(A + (rowA + ar + klr) * K + k0 + kcs * 8, &As[buf][ar * 64 + lane * 8]);
    }
#pragma unroll
    for (int i = 0; i < 4; ++i) {
      int br = wave * 32 + i * 8;
      ASYNC16(Bt + (rowB + br + klr) * K + k0 + kcs * 8, &Bs[buf][br * 64 + lane * 8]);
    }
  };

  stage(0, 0);
  int iters = K >> 6;
  for (int t = 0; t < iters; ++t) {
    int cur = t & 1;
    __syncthreads();
    if (t + 1 < iters) stage(cur ^ 1, (t + 1) * 64);
#pragma unroll
    for (int ks = 0; ks < 2; ++ks) {
      bf16x8 af[MT], bfr[4];
#pragma unroll
      for (int mt = 0; mt < MT; ++mt) {
        int row = wm * (MT * 16) + mt * 16 + qr;
        af[mt] = *(const bf16x8*)&As[cur][row * 64 + (((ks * 4 + quad) ^ (qr & 7)) << 3)];
      }
#pragma unroll
      for (int nt = 0; nt < 4; ++nt) {
        int row = wn * 64 + nt * 16 + qr;
        bfr[nt] = *(const bf16x8*)&Bs[cur][row * 64 + (((ks * 4 + quad) ^ (qr & 7)) << 3)];
      }
#pragma unroll
      for (int mt = 0; mt < MT; ++mt)
#pragma unroll
        for (int nt = 0; nt < 4; ++nt)
          acc[mt][nt] = MFMA16(af[mt], bfr[nt], acc[mt][nt]);
    }
    __syncthreads();
  }

  __syncthreads();

  if (mode == 1) {
    float* epf = (float*)smem;
#pragma unroll
    for (int nt = 0; nt < 4; ++nt) {
      int cl = wn * 64 + nt * 16 + qr;
      float bv = bias[rowB + cl];
#pragma unroll
      for (int mt = 0; mt < MT; ++mt) {
        int rl = wm * (MT * 16) + mt * 16 + quad * 4;
#pragma unroll
        for (int r = 0; r < 4; ++r)
          epf[(rl + r) * 132 + cl] = acc[mt][nt][r] + bv;
      }
    }
    __syncthreads();
    int rr = wave * 2 + (lane >> 5);
    int cc = (lane & 31) * 4;
#pragma unroll
    for (int p = 0; p < R / 8; ++p) {
      int row = p * 8 + rr;
      float4 v = *(const float4*)&epf[row * 132 + cc];
      *(float4*)&outf[(rowA + row) * 1024 + rowB + cc] = v;
    }
  } else if ((int)rowB < 2048) {
    float sc = ((int)rowB < 1024) ? QSCALE : 1.0f;
    u16* ep = smem;
#pragma unroll
    for (int nt = 0; nt < 4; ++nt) {
      int cl = wn * 64 + nt * 16 + qr;
      float bv = bias[rowB + cl];
#pragma unroll
      for (int mt = 0; mt < MT; ++mt) {
        int rl = wm * (MT * 16) + mt * 16 + quad * 4;
#pragma unroll
        for (int r = 0; r < 4; ++r)
          ep[(rl + r) * 136 + cl] = f2bf((acc[mt][nt][r] + bv) * sc);
      }
    }
    __syncthreads();
    int rr = wave * 4 + (lane >> 4);
    int cc = (lane & 15) * 8;
#pragma unroll
    for (int p = 0; p < R / 16; ++p) {
      int row = p * 16 + rr;
      u16x8v v = *(const u16x8v*)&ep[row * 136 + cc];
      *(u16x8v*)&qk[(rowA + row) * 2048 + rowB + cc] = v;
    }
  } else {
    u16* ep = smem;
#pragma unroll
    for (int nt = 0; nt < 4; ++nt) {
      int cl = wn * 64 + nt * 16 + qr;
      float bv = bias[rowB + cl];
#pragma unroll
      for (int mt = 0; mt < MT; ++mt) {
        int rl = wm * (MT * 16) + mt * 16 + quad * 4;
        ushort4 pv;
        pv.x = f2bf(acc[mt][nt][0] + bv);
        pv.y = f2bf(acc[mt][nt][1] + bv);
        pv.z = f2bf(acc[mt][nt][2] + bv);
        pv.w = f2bf(acc[mt][nt][3] + bv);
        *(ushort4*)&ep[cl * 136 + rl] = pv;
      }
    }
    __syncthreads();
    int batch = (int)(rowA >> 11);
    int n_base = (int)(rowA & 2047);
    int rr = wave * 4 + (lane >> 4);
    int cc = (lane & 15) * 8;
#pragma unroll
    for (int p = 0; p < 8; ++p) {
      int d = p * 16 + rr;
      int cglob = (int)rowB - 2048 + d;
      int bh_ = batch * 16 + (cglob >> 6);
      u16x8v v = *(const u16x8v*)&ep[d * 136 + cc];
      *(u16x8v*)&vtout[(size_t)bh_ * 131072 + (size_t)(cglob & 63) * 2048 + n_base + cc] = v;
    }
  }
}

// ------------- flash attention v12: v11 (52.0us) + deferred exp0 -------------
// v11 proved attn is chain-bound (sp-pipeline -3.2us at VGPR 64, occ 35%).
// v12 extends: QK0 and QK1 MFMA clusters issue back-to-back (z0 AND z1 held in
// regs, +16 VGPR ~= 80 total, <=128 so 4 waves/SIMD preserved); exp0 runs on
// the VALU while QK1's MFMAs drain; PV0 overlaps exp1 as in v11. MFMA pipe:
// [QK0][QK1][PV0][PV1] with only pack/LDS glue between clusters.
__global__ void __launch_bounds__(512, 4) attn_kernel(const u16* __restrict__ qkbuf,
                                                      const u16* __restrict__ vt,
                                                      u16* __restrict__ out) {
  __shared__ alignas(16) u16 kbuf[2][128 * 64];
  __shared__ alignas(16) u16 vbuf[2][64 * 128];
  __shared__ alignas(16) u16 pbuf[8][16 * 64];
  int bh = blockIdx.x;
  int b = bh >> 4, h = bh & 15;
  int m0 = blockIdx.y * 128;
  int tid = threadIdx.x;
  int lane = tid & 63, wave = tid >> 6;  // 8 waves
  int qr = lane & 15, quad = lane >> 4;

  const u16* kbase = qkbuf + (size_t)(b * SEQ) * 2048 + 1024 + h * 64;
  const u16* vtbase = vt + (size_t)bh * 64 * SEQ;
  u16* pw = &pbuf[wave][0];

  int klr = lane >> 3;
  int kcs = (lane & 7) ^ klr;

  const u16* qbase = qkbuf + (size_t)(b * SEQ + m0 + wave * 16) * 2048 + h * 64;
  bf16x8 qf[2];
#pragma unroll
  for (int ks = 0; ks < 2; ++ks)
    qf[ks] = *(const bf16x8*)&qbase[(size_t)qr * 2048 + ks * 32 + quad * 8];

  const bf16x8 vone = __builtin_bit_cast(bf16x8, (u16x8v)((u16)0x3F80));

  f32x4 o[4], l5;
  l5 = (f32x4){0.f, 0.f, 0.f, 0.f};
#pragma unroll
  for (int dt = 0; dt < 4; ++dt) o[dt] = (f32x4){0.f, 0.f, 0.f, 0.f};

  auto stage = [&](int buf, int n0) {
#pragma unroll
    for (int i = 0; i < 2; ++i) {
      int kr = wave * 16 + i * 8 + klr;
      ASYNC16(kbase + (size_t)(n0 + kr) * 2048 + kcs * 8,
              &kbuf[buf][(wave * 16 + i * 8) * 64 + lane * 8]);
    }
#pragma unroll
    for (int i = 0; i < 2; ++i) {
      int vr = wave * 8 + i * 4 + (lane >> 4);
      int vcs = ((lane & 7) ^ (vr & 7)) | (lane & 8);
      ASYNC16(vtbase + (size_t)vr * 2048 + n0 + vcs * 8,
              &vbuf[buf][(wave * 8 + i * 4) * 128 + lane * 8]);
    }
  };

  stage(0, 0);

  for (int t = 0; t < 16; ++t) {
    int cur = t & 1;
    __syncthreads();

    if (t + 1 < 16) stage(cur ^ 1, (t + 1) * 128);

    const u16* kb0 = &kbuf[cur][0];
    const u16* kb1 = &kbuf[cur][64 * 64];
    const u16* vb = &vbuf[cur][0];

    // ---- QK0: MFMAs, exp DEFERRED (z0 in regs) ----
    f32x4 z0[4];
    {
      bf16x8 kf[4][2];
#pragma unroll
      for (int nt = 0; nt < 4; ++nt)
#pragma unroll
        for (int ks = 0; ks < 2; ++ks)
          kf[nt][ks] =
              *(const bf16x8*)&kb0[(nt * 16 + qr) * 64 + (((ks * 4 + quad) ^ (qr & 7)) << 3)];
#pragma unroll
      for (int nt = 0; nt < 4; ++nt) {
        f32x4 z = (f32x4){0.f, 0.f, 0.f, 0.f};
        z = MFMA16(kf[nt][0], qf[0], z);
        z0[nt] = MFMA16(kf[nt][1], qf[1], z);
      }
    }

    // ---- QK1: MFMAs, exp DEFERRED (z1 in regs) ----
    f32x4 z1[4];
    {
      bf16x8 kg[4][2];
#pragma unroll
      for (int nt = 0; nt < 4; ++nt)
#pragma unroll
        for (int ks = 0; ks < 2; ++ks)
          kg[nt][ks] =
              *(const bf16x8*)&kb1[(nt * 16 + qr) * 64 + (((ks * 4 + quad) ^ (qr & 7)) << 3)];
#pragma unroll
      for (int nt = 0; nt < 4; ++nt) {
        f32x4 z = (f32x4){0.f, 0.f, 0.f, 0.f};
        z = MFMA16(kg[nt][0], qf[0], z);
        z1[nt] = MFMA16(kg[nt][1], qf[1], z);
      }
    }

    // ---- exp0 + pack -> P0 (VALU; overlaps QK1 MFMA drain) ----
#pragma unroll
    for (int nt = 0; nt < 4; ++nt) {
      f32x4 z = z0[nt];
      float p0 = __builtin_amdgcn_exp2f(z[0]);
      float p1 = __builtin_amdgcn_exp2f(z[1]);
      float p2 = __builtin_amdgcn_exp2f(z[2]);
      float p3 = __builtin_amdgcn_exp2f(z[3]);
      uint2 pk;
      pk.x = cvt2(p0, p1);
      pk.y = cvt2(p2, p3);
      int nb = nt * 16 + quad * 4;
      int addr = qr * 64 + ((((nb >> 3) ^ (qr & 7)) << 3) | (nb & 7));
      *(uint2*)&pw[addr] = pk;
    }

    // ---- pf0 (in-order wave-private LDS: completes before P1 write) + vf0 ----
    bf16x8 pf0[2];
#pragma unroll
    for (int ks = 0; ks < 2; ++ks)
      pf0[ks] = *(const bf16x8*)&pw[qr * 64 + (((ks * 4 + quad) ^ (qr & 7)) << 3)];

    bf16x8 vf0[4][2];
#pragma unroll
    for (int dt = 0; dt < 4; ++dt)
#pragma unroll
      for (int ks = 0; ks < 2; ++ks)
        vf0[dt][ks] = *(const bf16x8*)&vb[(dt * 16 + qr) * 128 +
                                          ((((ks * 4 + quad) ^ (qr & 7))) << 3)];

    // ---- PV0 ----
#pragma unroll
    for (int dt = 0; dt < 4; ++dt) {
      o[dt] = MFMA16(pf0[0], vf0[dt][0], o[dt]);
      o[dt] = MFMA16(pf0[1], vf0[dt][1], o[dt]);
    }
    l5 = MFMA16(pf0[0], vone, l5);
    l5 = MFMA16(pf0[1], vone, l5);

    // ---- exp1 + pack -> P1 (VALU; overlaps PV0 drain) ----
#pragma unroll
    for (int nt = 0; nt < 4; ++nt) {
      f32x4 z = z1[nt];
      float p0 = __builtin_amdgcn_exp2f(z[0]);
      float p1 = __builtin_amdgcn_exp2f(z[1]);
      float p2 = __builtin_amdgcn_exp2f(z[2]);
      float p3 = __builtin_amdgcn_exp2f(z[3]);
      uint2 pk;
      pk.x = cvt2(p0, p1);
      pk.y = cvt2(p2, p3);
      int nb = nt * 16 + quad * 4;
      int addr = qr * 64 + ((((nb >> 3) ^ (qr & 7)) << 3) | (nb & 7));
      *(uint2*)&pw[addr] = pk;
    }

    // ---- pf1 + vf1, then PV1 ----
    bf16x8 pf1[2];
#pragma unroll
    for (int ks = 0; ks < 2; ++ks)
      pf1[ks] = *(const bf16x8*)&pw[qr * 64 + (((ks * 4 + quad) ^ (qr & 7)) << 3)];

    bf16x8 vf1[4][2];
#pragma unroll
    for (int dt = 0; dt < 4; ++dt)
#pragma unroll
      for (int ks = 0; ks < 2; ++ks)
        vf1[dt][ks] = *(const bf16x8*)&vb[(dt * 16 + qr) * 128 +
                                          ((8 + (((ks * 4 + quad) ^ (qr & 7)))) << 3)];

#pragma unroll
    for (int dt = 0; dt < 4; ++dt) {
      o[dt] = MFMA16(pf1[0], vf1[dt][0], o[dt]);
      o[dt] = MFMA16(pf1[1], vf1[dt][1], o[dt]);
    }
    l5 = MFMA16(pf1[0], vone, l5);
    l5 = MFMA16(pf1[1], vone, l5);
  }

  u16* obase = out + (size_t)(b * SEQ + m0 + wave * 16) * CH + h * 64;
#pragma unroll
  for (int r = 0; r < 4; ++r) {
    float inv = 1.0f / l5[r];
#pragma unroll
    for (int dt = 0; dt < 4; ++dt)
      obase[(size_t)(quad * 4 + r) * CH + dt * 16 + qr] = f2bf(o[dt][r] * inv);
  }
}

extern "C" void kernel_launch(void* const* d_in, const int* in_sizes, int n_in,
                              void* d_out, int out_size, void* d_ws, size_t ws_size,
                              hipStream_t stream) {
  const float* x      = (const float*)d_in[0];
  const float* qkv_w  = (const float*)d_in[1];
  const float* qkv_b  = (const float*)d_in[2];
  const float* proj_w = (const float*)d_in[3];
  const float* proj_b = (const float*)d_in[4];
  float* out = (float*)d_out;

  char* w = (char*)d_ws;
  // ws layout (42 MB):
  //   qkqk  : 4096x2048 bf16 (Q scaled | K, stride 2048) = 16777216 B
  //   xb    : 4096x1024 bf16 = 8388608 B (reused as attn_bf after gemm1)
  //   wprojt: 1024x1024 bf16 = 2097152 B
  //   wqkvt : 3072x1024 bf16 = 6291456 B
  //   vt    : (B*H)x64x2048 bf16 = 8388608 B (written directly by gemm1 epilogue)
  u16* qkqk   = (u16*)w;
  u16* xb     = (u16*)(w + 16777216);
  u16* wprojt = (u16*)(w + 25165824);
  u16* wqkvt  = (u16*)(w + 27262976);
  u16* vt     = (u16*)(w + 33554432);
  u16* attn_bf = xb;

  prep_kernel<<<5120, 256, 0, stream>>>(x, qkv_w, proj_w, xb, wqkvt, wprojt);
  // qkv = x @ qkv_w + b; Q scaled; QK -> qkqk (stride 2048), V -> vt (transposed)
  gemm_kernel<4><<<dim3(24, 32), 256, 0, stream>>>(xb, wqkvt, qkv_b, qkqk, vt, nullptr, 1024, 0);
  attn_kernel<<<dim3(32, 16), 512, 0, stream>>>(qkqk, vt, attn_bf);
  // out = attn @ proj_w + b (fp32); MT=2 at (8,64): 2 blocks/CU overlap wins (r10)
  gemm_kernel<2><<<dim3(8, 64), 256, 0, stream>>>(attn_bf, wprojt, proj_b, nullptr, nullptr, out, 1024, 1);
}

// Round 12
// 180.875 us; speedup vs baseline: 1.0287x; 1.0287x over previous
//
#include <hip/hip_runtime.h>
#include <cstdint>
#include <cstddef>

typedef __bf16 bf16x8 __attribute__((ext_vector_type(8)));
typedef __bf16 bf16x2v __attribute__((ext_vector_type(2)));
typedef unsigned short u16;
typedef u16 u16x8v __attribute__((ext_vector_type(8)));
typedef float  f32x4  __attribute__((ext_vector_type(4)));
typedef unsigned int u32;

#define MFMA16(a, b, c) __builtin_amdgcn_mfma_f32_16x16x32_bf16((a), (b), (c), 0, 0, 0)
#define ASYNC16(g, l)                                                              \
  __builtin_amdgcn_global_load_lds(                                                \
      (const __attribute__((address_space(1))) unsigned int*)(g),                  \
      (__attribute__((address_space(3))) unsigned int*)(l), 16, 0, 0)

__device__ __forceinline__ u16 f2bf(float f) {
  unsigned u = __builtin_bit_cast(unsigned, f);
  u += 0x7fffu + ((u >> 16) & 1u);
  return (u16)(u >> 16);
}

// packed fp32x2 -> bf16x2 (RNE) via hardware cvt
__device__ __forceinline__ u32 cvt2(float a, float b) {
  bf16x2v t;
  t[0] = (__bf16)a;
  t[1] = (__bf16)b;
  return __builtin_bit_cast(u32, t);
}

#define SEQ 2048
#define CH  1024
#define NH  16
#define HD  64
// log2(e) / sqrt(64) folded into stored Q so softmax uses exp2
#define QSCALE 0.18033688011112042f

// ------------- fused prep: cast x + transpose-cast qkv_w + proj_w -------------
// (round-2 original, measured-best)
__global__ void __launch_bounds__(256) prep_kernel(const float* __restrict__ x,
                                                   const float* __restrict__ qkv_w,
                                                   const float* __restrict__ proj_w,
                                                   u16* __restrict__ xb,
                                                   u16* __restrict__ wqkvt,
                                                   u16* __restrict__ wprojt) {
  __shared__ u16 t[64][68];
  int bx = blockIdx.x;
  int tx = threadIdx.x;
  if (bx < 4096) {
    int i = bx * 256 + tx;
    float4 v = ((const float4*)x)[i];
    ushort4 o;
    o.x = f2bf(v.x); o.y = f2bf(v.y); o.z = f2bf(v.z); o.w = f2bf(v.w);
    ((ushort4*)xb)[i] = o;
    return;
  }
  const float* in; u16* out; int R, C, c0, r0;
  if (bx < 4096 + 768) {
    int i = bx - 4096;
    in = qkv_w; out = wqkvt; R = 1024; C = 3072;
    c0 = (i % 48) * 64; r0 = (i / 48) * 64;
  } else {
    int i = bx - 4864;
    in = proj_w; out = wprojt; R = 1024; C = 1024;
    c0 = (i % 16) * 64; r0 = (i / 16) * 64;
  }
  int rr = tx >> 6, cc = tx & 63;
#pragma unroll
  for (int i = 0; i < 16; ++i) {
    int r = i * 4 + rr;
    t[r][cc] = f2bf(in[(size_t)(r0 + r) * C + c0 + cc]);
  }
  __syncthreads();
#pragma unroll
  for (int i = 0; i < 16; ++i) {
    int r = i * 4 + rr;
    out[(size_t)(c0 + r) * R + r0 + cc] = t[cc][r];
  }
}

// ------------- GEMM v4 (round-2 exact, measured-best): BK=64, XOR-swizzled LDS,
//               double-buffered staging, two barriers/iter, coalesced epilogue ----
// Session lessons: XCD swizzle regresses (r3); single-barrier +3us (r4);
// 256²/8-phase neutral (r8); gemm2 MT=4 at (8,32) within noise (r10/r11 —
// non-attn run noise is ±5us, sub-5us GEMM deltas unreadable here).
// CLOSED: MT=4 gemm1 (24,32), MT=2 gemm2 (8,64).
template <int MT>
__global__ void __launch_bounds__(256) gemm_kernel(const u16* __restrict__ A,
                                                   const u16* __restrict__ Bt,
                                                   const float* __restrict__ bias,
                                                   u16* __restrict__ qk,
                                                   u16* __restrict__ vtout,
                                                   float* __restrict__ outf,
                                                   int K, int mode) {
  constexpr int R = MT * 32;
  __shared__ alignas(16) u16 smem[2 * R * 64 + 2 * 128 * 64];
  auto As = (u16(*)[R * 64])smem;
  auto Bs = (u16(*)[128 * 64])(smem + 2 * R * 64);
  int tid = threadIdx.x;
  int lane = tid & 63, wave = tid >> 6;
  int wm = wave >> 1, wn = wave & 1;
  int qr = lane & 15, quad = lane >> 4;
  size_t rowA = (size_t)blockIdx.y * R;
  size_t rowB = (size_t)blockIdx.x * 128;

  int klr = lane >> 3;
  int kcs = (lane & 7) ^ klr;

  f32x4 acc[MT][4];
#pragma unroll
  for (int mt = 0; mt < MT; ++mt)
#pragma unroll
    for (int nt = 0; nt < 4; ++nt) acc[mt][nt] = (f32x4){0.f, 0.f, 0.f, 0.f};

  auto stage = [&](int buf, int k0) {
#pragma unroll
    for (int i = 0; i < R / 32; ++i) {
      int ar = wave * (R / 4) + i * 8;
      ASYNC16(A + (rowA + ar + klr) * K + k0 + kcs * 8, &As[buf][ar * 64 + lane * 8]);
    }
#pragma unroll
    for (int i = 0; i < 4; ++i) {
      int br = wave * 32 + i * 8;
      ASYNC16(Bt + (rowB + br + klr) * K + k0 + kcs * 8, &Bs[buf][br * 64 + lane * 8]);
    }
  };

  stage(0, 0);
  int iters = K >> 6;
  for (int t = 0; t < iters; ++t) {
    int cur = t & 1;
    __syncthreads();
    if (t + 1 < iters) stage(cur ^ 1, (t + 1) * 64);
#pragma unroll
    for (int ks = 0; ks < 2; ++ks) {
      bf16x8 af[MT], bfr[4];
#pragma unroll
      for (int mt = 0; mt < MT; ++mt) {
        int row = wm * (MT * 16) + mt * 16 + qr;
        af[mt] = *(const bf16x8*)&As[cur][row * 64 + (((ks * 4 + quad) ^ (qr & 7)) << 3)];
      }
#pragma unroll
      for (int nt = 0; nt < 4; ++nt) {
        int row = wn * 64 + nt * 16 + qr;
        bfr[nt] = *(const bf16x8*)&Bs[cur][row * 64 + (((ks * 4 + quad) ^ (qr & 7)) << 3)];
      }
#pragma unroll
      for (int mt = 0; mt < MT; ++mt)
#pragma unroll
        for (int nt = 0; nt < 4; ++nt)
          acc[mt][nt] = MFMA16(af[mt], bfr[nt], acc[mt][nt]);
    }
    __syncthreads();
  }

  __syncthreads();

  if (mode == 1) {
    float* epf = (float*)smem;
#pragma unroll
    for (int nt = 0; nt < 4; ++nt) {
      int cl = wn * 64 + nt * 16 + qr;
      float bv = bias[rowB + cl];
#pragma unroll
      for (int mt = 0; mt < MT; ++mt) {
        int rl = wm * (MT * 16) + mt * 16 + quad * 4;
#pragma unroll
        for (int r = 0; r < 4; ++r)
          epf[(rl + r) * 132 + cl] = acc[mt][nt][r] + bv;
      }
    }
    __syncthreads();
    int rr = wave * 2 + (lane >> 5);
    int cc = (lane & 31) * 4;
#pragma unroll
    for (int p = 0; p < R / 8; ++p) {
      int row = p * 8 + rr;
      float4 v = *(const float4*)&epf[row * 132 + cc];
      *(float4*)&outf[(rowA + row) * 1024 + rowB + cc] = v;
    }
  } else if ((int)rowB < 2048) {
    float sc = ((int)rowB < 1024) ? QSCALE : 1.0f;
    u16* ep = smem;
#pragma unroll
    for (int nt = 0; nt < 4; ++nt) {
      int cl = wn * 64 + nt * 16 + qr;
      float bv = bias[rowB + cl];
#pragma unroll
      for (int mt = 0; mt < MT; ++mt) {
        int rl = wm * (MT * 16) + mt * 16 + quad * 4;
#pragma unroll
        for (int r = 0; r < 4; ++r)
          ep[(rl + r) * 136 + cl] = f2bf((acc[mt][nt][r] + bv) * sc);
      }
    }
    __syncthreads();
    int rr = wave * 4 + (lane >> 4);
    int cc = (lane & 15) * 8;
#pragma unroll
    for (int p = 0; p < R / 16; ++p) {
      int row = p * 16 + rr;
      u16x8v v = *(const u16x8v*)&ep[row * 136 + cc];
      *(u16x8v*)&qk[(rowA + row) * 2048 + rowB + cc] = v;
    }
  } else {
    u16* ep = smem;
#pragma unroll
    for (int nt = 0; nt < 4; ++nt) {
      int cl = wn * 64 + nt * 16 + qr;
      float bv = bias[rowB + cl];
#pragma unroll
      for (int mt = 0; mt < MT; ++mt) {
        int rl = wm * (MT * 16) + mt * 16 + quad * 4;
        ushort4 pv;
        pv.x = f2bf(acc[mt][nt][0] + bv);
        pv.y = f2bf(acc[mt][nt][1] + bv);
        pv.z = f2bf(acc[mt][nt][2] + bv);
        pv.w = f2bf(acc[mt][nt][3] + bv);
        *(ushort4*)&ep[cl * 136 + rl] = pv;
      }
    }
    __syncthreads();
    int batch = (int)(rowA >> 11);
    int n_base = (int)(rowA & 2047);
    int rr = wave * 4 + (lane >> 4);
    int cc = (lane & 15) * 8;
#pragma unroll
    for (int p = 0; p < 8; ++p) {
      int d = p * 16 + rr;
      int cglob = (int)rowB - 2048 + d;
      int bh_ = batch * 16 + (cglob >> 6);
      u16x8v v = *(const u16x8v*)&ep[d * 136 + cc];
      *(u16x8v*)&vtout[(size_t)bh_ * 131072 + (size_t)(cglob & 63) * 2048 + n_base + cc] = v;
    }
  }
}

// ------------- flash attention v11 (round-10 attn, measured-best 52.0us) -------
// 8 waves x 16 q-rows (occ 35%, VGPR 64) + single-deferred-exp sp-pipeline:
// QK0+exp0 -> [QK1 MFMAs, exp1 deferred] -> PV0 (overlaps exp1's VALU) -> exp1
// -> PV1. v12's double-deferral (exp0 also deferred) REGRESSED +1.6us: QK0/QK1
// back-to-back serializes the MFMA pipe with no VALU fill — keep v11's
// asymmetric schedule.
__global__ void __launch_bounds__(512, 4) attn_kernel(const u16* __restrict__ qkbuf,
                                                      const u16* __restrict__ vt,
                                                      u16* __restrict__ out) {
  __shared__ alignas(16) u16 kbuf[2][128 * 64];
  __shared__ alignas(16) u16 vbuf[2][64 * 128];
  __shared__ alignas(16) u16 pbuf[8][16 * 64];
  int bh = blockIdx.x;
  int b = bh >> 4, h = bh & 15;
  int m0 = blockIdx.y * 128;
  int tid = threadIdx.x;
  int lane = tid & 63, wave = tid >> 6;  // 8 waves
  int qr = lane & 15, quad = lane >> 4;

  const u16* kbase = qkbuf + (size_t)(b * SEQ) * 2048 + 1024 + h * 64;
  const u16* vtbase = vt + (size_t)bh * 64 * SEQ;
  u16* pw = &pbuf[wave][0];

  int klr = lane >> 3;
  int kcs = (lane & 7) ^ klr;

  const u16* qbase = qkbuf + (size_t)(b * SEQ + m0 + wave * 16) * 2048 + h * 64;
  bf16x8 qf[2];
#pragma unroll
  for (int ks = 0; ks < 2; ++ks)
    qf[ks] = *(const bf16x8*)&qbase[(size_t)qr * 2048 + ks * 32 + quad * 8];

  const bf16x8 vone = __builtin_bit_cast(bf16x8, (u16x8v)((u16)0x3F80));

  f32x4 o[4], l5;
  l5 = (f32x4){0.f, 0.f, 0.f, 0.f};
#pragma unroll
  for (int dt = 0; dt < 4; ++dt) o[dt] = (f32x4){0.f, 0.f, 0.f, 0.f};

  auto stage = [&](int buf, int n0) {
#pragma unroll
    for (int i = 0; i < 2; ++i) {
      int kr = wave * 16 + i * 8 + klr;
      ASYNC16(kbase + (size_t)(n0 + kr) * 2048 + kcs * 8,
              &kbuf[buf][(wave * 16 + i * 8) * 64 + lane * 8]);
    }
#pragma unroll
    for (int i = 0; i < 2; ++i) {
      int vr = wave * 8 + i * 4 + (lane >> 4);
      int vcs = ((lane & 7) ^ (vr & 7)) | (lane & 8);
      ASYNC16(vtbase + (size_t)vr * 2048 + n0 + vcs * 8,
              &vbuf[buf][(wave * 8 + i * 4) * 128 + lane * 8]);
    }
  };

  stage(0, 0);

  for (int t = 0; t < 16; ++t) {
    int cur = t & 1;
    __syncthreads();

    if (t + 1 < 16) stage(cur ^ 1, (t + 1) * 128);

    const u16* kb0 = &kbuf[cur][0];
    const u16* kb1 = &kbuf[cur][64 * 64];
    const u16* vb = &vbuf[cur][0];

    // ---- sp0: QK + exp + pack -> P0 ----
    {
      bf16x8 kf[4][2];
#pragma unroll
      for (int nt = 0; nt < 4; ++nt)
#pragma unroll
        for (int ks = 0; ks < 2; ++ks)
          kf[nt][ks] =
              *(const bf16x8*)&kb0[(nt * 16 + qr) * 64 + (((ks * 4 + quad) ^ (qr & 7)) << 3)];
#pragma unroll
      for (int nt = 0; nt < 4; ++nt) {
        f32x4 z = (f32x4){0.f, 0.f, 0.f, 0.f};
        z = MFMA16(kf[nt][0], qf[0], z);
        z = MFMA16(kf[nt][1], qf[1], z);
        float p0 = __builtin_amdgcn_exp2f(z[0]);
        float p1 = __builtin_amdgcn_exp2f(z[1]);
        float p2 = __builtin_amdgcn_exp2f(z[2]);
        float p3 = __builtin_amdgcn_exp2f(z[3]);
        uint2 pk;
        pk.x = cvt2(p0, p1);
        pk.y = cvt2(p2, p3);
        int nb = nt * 16 + quad * 4;
        int addr = qr * 64 + ((((nb >> 3) ^ (qr & 7)) << 3) | (nb & 7));
        *(uint2*)&pw[addr] = pk;
      }
    }

    // ---- read pf0 (completes before P1 write; wave-private in-order LDS) + vf0 ----
    bf16x8 pf0[2];
#pragma unroll
    for (int ks = 0; ks < 2; ++ks)
      pf0[ks] = *(const bf16x8*)&pw[qr * 64 + (((ks * 4 + quad) ^ (qr & 7)) << 3)];

    bf16x8 vf0[4][2];
#pragma unroll
    for (int dt = 0; dt < 4; ++dt)
#pragma unroll
      for (int ks = 0; ks < 2; ++ks)
        vf0[dt][ks] = *(const bf16x8*)&vb[(dt * 16 + qr) * 128 +
                                          ((((ks * 4 + quad) ^ (qr & 7))) << 3)];

    // ---- sp1 QK: MFMAs now, exp deferred (z1 in 16 VGPRs) ----
    f32x4 z1[4];
    {
      bf16x8 kg[4][2];
#pragma unroll
      for (int nt = 0; nt < 4; ++nt)
#pragma unroll
        for (int ks = 0; ks < 2; ++ks)
          kg[nt][ks] =
              *(const bf16x8*)&kb1[(nt * 16 + qr) * 64 + (((ks * 4 + quad) ^ (qr & 7)) << 3)];
#pragma unroll
      for (int nt = 0; nt < 4; ++nt) {
        f32x4 z = (f32x4){0.f, 0.f, 0.f, 0.f};
        z = MFMA16(kg[nt][0], qf[0], z);
        z1[nt] = MFMA16(kg[nt][1], qf[1], z);
      }
    }

    // ---- PV0 (independent of z1): fills MFMA pipe while exp1 inputs settle ----
#pragma unroll
    for (int dt = 0; dt < 4; ++dt) {
      o[dt] = MFMA16(pf0[0], vf0[dt][0], o[dt]);
      o[dt] = MFMA16(pf0[1], vf0[dt][1], o[dt]);
    }
    l5 = MFMA16(pf0[0], vone, l5);
    l5 = MFMA16(pf0[1], vone, l5);

    // ---- exp1 + pack -> P1 (VALU; overlaps PV0 drain) ----
#pragma unroll
    for (int nt = 0; nt < 4; ++nt) {
      f32x4 z = z1[nt];
      float p0 = __builtin_amdgcn_exp2f(z[0]);
      float p1 = __builtin_amdgcn_exp2f(z[1]);
      float p2 = __builtin_amdgcn_exp2f(z[2]);
      float p3 = __builtin_amdgcn_exp2f(z[3]);
      uint2 pk;
      pk.x = cvt2(p0, p1);
      pk.y = cvt2(p2, p3);
      int nb = nt * 16 + quad * 4;
      int addr = qr * 64 + ((((nb >> 3) ^ (qr & 7)) << 3) | (nb & 7));
      *(uint2*)&pw[addr] = pk;
    }

    // ---- pf1 + vf1, then PV1 ----
    bf16x8 pf1[2];
#pragma unroll
    for (int ks = 0; ks < 2; ++ks)
      pf1[ks] = *(const bf16x8*)&pw[qr * 64 + (((ks * 4 + quad) ^ (qr & 7)) << 3)];

    bf16x8 vf1[4][2];
#pragma unroll
    for (int dt = 0; dt < 4; ++dt)
#pragma unroll
      for (int ks = 0; ks < 2; ++ks)
        vf1[dt][ks] = *(const bf16x8*)&vb[(dt * 16 + qr) * 128 +
                                          ((8 + (((ks * 4 + quad) ^ (qr & 7)))) << 3)];

#pragma unroll
    for (int dt = 0; dt < 4; ++dt) {
      o[dt] = MFMA16(pf1[0], vf1[dt][0], o[dt]);
      o[dt] = MFMA16(pf1[1], vf1[dt][1], o[dt]);
    }
    l5 = MFMA16(pf1[0], vone, l5);
    l5 = MFMA16(pf1[1], vone, l5);
  }

  u16* obase = out + (size_t)(b * SEQ + m0 + wave * 16) * CH + h * 64;
#pragma unroll
  for (int r = 0; r < 4; ++r) {
    float inv = 1.0f / l5[r];
#pragma unroll
    for (int dt = 0; dt < 4; ++dt)
      obase[(size_t)(quad * 4 + r) * CH + dt * 16 + qr] = f2bf(o[dt][r] * inv);
  }
}

extern "C" void kernel_launch(void* const* d_in, const int* in_sizes, int n_in,
                              void* d_out, int out_size, void* d_ws, size_t ws_size,
                              hipStream_t stream) {
  const float* x      = (const float*)d_in[0];
  const float* qkv_w  = (const float*)d_in[1];
  const float* qkv_b  = (const float*)d_in[2];
  const float* proj_w = (const float*)d_in[3];
  const float* proj_b = (const float*)d_in[4];
  float* out = (float*)d_out;

  char* w = (char*)d_ws;
  // ws layout (42 MB):
  //   qkqk  : 4096x2048 bf16 (Q scaled | K, stride 2048) = 16777216 B
  //   xb    : 4096x1024 bf16 = 8388608 B (reused as attn_bf after gemm1)
  //   wprojt: 1024x1024 bf16 = 2097152 B
  //   wqkvt : 3072x1024 bf16 = 6291456 B
  //   vt    : (B*H)x64x2048 bf16 = 8388608 B (written directly by gemm1 epilogue)
  u16* qkqk   = (u16*)w;
  u16* xb     = (u16*)(w + 16777216);
  u16* wprojt = (u16*)(w + 25165824);
  u16* wqkvt  = (u16*)(w + 27262976);
  u16* vt     = (u16*)(w + 33554432);
  u16* attn_bf = xb;

  prep_kernel<<<5120, 256, 0, stream>>>(x, qkv_w, proj_w, xb, wqkvt, wprojt);
  // qkv = x @ qkv_w + b; Q scaled; QK -> qkqk (stride 2048), V -> vt (transposed)
  gemm_kernel<4><<<dim3(24, 32), 256, 0, stream>>>(xb, wqkvt, qkv_b, qkqk, vt, nullptr, 1024, 0);
  attn_kernel<<<dim3(32, 16), 512, 0, stream>>>(qkqk, vt, attn_bf);
  // out = attn @ proj_w + b (fp32); MT=2 at (8,64)
  gemm_kernel<2><<<dim3(8, 64), 256, 0, stream>>>(attn_bf, wprojt, proj_b, nullptr, nullptr, out, 1024, 1);
}

// Round 13
// 179.729 us; speedup vs baseline: 1.0352x; 1.0064x over previous
//
#include <hip/hip_runtime.h>
#include <cstdint>
#include <cstddef>

typedef __bf16 bf16x8 __attribute__((ext_vector_type(8)));
typedef __bf16 bf16x2v __attribute__((ext_vector_type(2)));
typedef unsigned short u16;
typedef u16 u16x8v __attribute__((ext_vector_type(8)));
typedef float  f32x4  __attribute__((ext_vector_type(4)));
typedef unsigned int u32;

#define MFMA16(a, b, c) __builtin_amdgcn_mfma_f32_16x16x32_bf16((a), (b), (c), 0, 0, 0)
#define ASYNC16(g, l)                                                              \
  __builtin_amdgcn_global_load_lds(                                                \
      (const __attribute__((address_space(1))) unsigned int*)(g),                  \
      (__attribute__((address_space(3))) unsigned int*)(l), 16, 0, 0)

__device__ __forceinline__ u16 f2bf(float f) {
  unsigned u = __builtin_bit_cast(unsigned, f);
  u += 0x7fffu + ((u >> 16) & 1u);
  return (u16)(u >> 16);
}

// packed fp32x2 -> bf16x2 (RNE) via hardware cvt
__device__ __forceinline__ u32 cvt2(float a, float b) {
  bf16x2v t;
  t[0] = (__bf16)a;
  t[1] = (__bf16)b;
  return __builtin_bit_cast(u32, t);
}

#define SEQ 2048
#define CH  1024
#define NH  16
#define HD  64
// log2(e) / sqrt(64) folded into stored Q so softmax uses exp2
#define QSCALE 0.18033688011112042f

// ------------- fused prep: cast x + transpose-cast qkv_w + proj_w -------------
// (round-2 original, measured-best)
__global__ void __launch_bounds__(256) prep_kernel(const float* __restrict__ x,
                                                   const float* __restrict__ qkv_w,
                                                   const float* __restrict__ proj_w,
                                                   u16* __restrict__ xb,
                                                   u16* __restrict__ wqkvt,
                                                   u16* __restrict__ wprojt) {
  __shared__ u16 t[64][68];
  int bx = blockIdx.x;
  int tx = threadIdx.x;
  if (bx < 4096) {
    int i = bx * 256 + tx;
    float4 v = ((const float4*)x)[i];
    ushort4 o;
    o.x = f2bf(v.x); o.y = f2bf(v.y); o.z = f2bf(v.z); o.w = f2bf(v.w);
    ((ushort4*)xb)[i] = o;
    return;
  }
  const float* in; u16* out; int R, C, c0, r0;
  if (bx < 4096 + 768) {
    int i = bx - 4096;
    in = qkv_w; out = wqkvt; R = 1024; C = 3072;
    c0 = (i % 48) * 64; r0 = (i / 48) * 64;
  } else {
    int i = bx - 4864;
    in = proj_w; out = wprojt; R = 1024; C = 1024;
    c0 = (i % 16) * 64; r0 = (i / 16) * 64;
  }
  int rr = tx >> 6, cc = tx & 63;
#pragma unroll
  for (int i = 0; i < 16; ++i) {
    int r = i * 4 + rr;
    t[r][cc] = f2bf(in[(size_t)(r0 + r) * C + c0 + cc]);
  }
  __syncthreads();
#pragma unroll
  for (int i = 0; i < 16; ++i) {
    int r = i * 4 + rr;
    out[(size_t)(c0 + r) * R + r0 + cc] = t[cc][r];
  }
}

// ------------- GEMM v4 (round-2 exact, measured-best): BK=64, XOR-swizzled LDS,
//               double-buffered staging, two barriers/iter, coalesced epilogue ----
// Session lessons: XCD swizzle regresses (r3); single-barrier +3us (r4);
// 256²/8-phase neutral (r8); gemm2 MT=4 at (8,32) within noise (r10/r11 —
// non-attn run noise is ±5us, sub-5us GEMM deltas unreadable here).
// CLOSED: MT=4 gemm1 (24,32), MT=2 gemm2 (8,64).
template <int MT>
__global__ void __launch_bounds__(256) gemm_kernel(const u16* __restrict__ A,
                                                   const u16* __restrict__ Bt,
                                                   const float* __restrict__ bias,
                                                   u16* __restrict__ qk,
                                                   u16* __restrict__ vtout,
                                                   float* __restrict__ outf,
                                                   int K, int mode) {
  constexpr int R = MT * 32;
  __shared__ alignas(16) u16 smem[2 * R * 64 + 2 * 128 * 64];
  auto As = (u16(*)[R * 64])smem;
  auto Bs = (u16(*)[128 * 64])(smem + 2 * R * 64);
  int tid = threadIdx.x;
  int lane = tid & 63, wave = tid >> 6;
  int wm = wave >> 1, wn = wave & 1;
  int qr = lane & 15, quad = lane >> 4;
  size_t rowA = (size_t)blockIdx.y * R;
  size_t rowB = (size_t)blockIdx.x * 128;

  int klr = lane >> 3;
  int kcs = (lane & 7) ^ klr;

  f32x4 acc[MT][4];
#pragma unroll
  for (int mt = 0; mt < MT; ++mt)
#pragma unroll
    for (int nt = 0; nt < 4; ++nt) acc[mt][nt] = (f32x4){0.f, 0.f, 0.f, 0.f};

  auto stage = [&](int buf, int k0) {
#pragma unroll
    for (int i = 0; i < R / 32; ++i) {
      int ar = wave * (R / 4) + i * 8;
      ASYNC16(A + (rowA + ar + klr) * K + k0 + kcs * 8, &As[buf][ar * 64 + lane * 8]);
    }
#pragma unroll
    for (int i = 0; i < 4; ++i) {
      int br = wave * 32 + i * 8;
      ASYNC16(Bt + (rowB + br + klr) * K + k0 + kcs * 8, &Bs[buf][br * 64 + lane * 8]);
    }
  };

  stage(0, 0);
  int iters = K >> 6;
  for (int t = 0; t < iters; ++t) {
    int cur = t & 1;
    __syncthreads();
    if (t + 1 < iters) stage(cur ^ 1, (t + 1) * 64);
#pragma unroll
    for (int ks = 0; ks < 2; ++ks) {
      bf16x8 af[MT], bfr[4];
#pragma unroll
      for (int mt = 0; mt < MT; ++mt) {
        int row = wm * (MT * 16) + mt * 16 + qr;
        af[mt] = *(const bf16x8*)&As[cur][row * 64 + (((ks * 4 + quad) ^ (qr & 7)) << 3)];
      }
#pragma unroll
      for (int nt = 0; nt < 4; ++nt) {
        int row = wn * 64 + nt * 16 + qr;
        bfr[nt] = *(const bf16x8*)&Bs[cur][row * 64 + (((ks * 4 + quad) ^ (qr & 7)) << 3)];
      }
#pragma unroll
      for (int mt = 0; mt < MT; ++mt)
#pragma unroll
        for (int nt = 0; nt < 4; ++nt)
          acc[mt][nt] = MFMA16(af[mt], bfr[nt], acc[mt][nt]);
    }
    __syncthreads();
  }

  __syncthreads();

  if (mode == 1) {
    float* epf = (float*)smem;
#pragma unroll
    for (int nt = 0; nt < 4; ++nt) {
      int cl = wn * 64 + nt * 16 + qr;
      float bv = bias[rowB + cl];
#pragma unroll
      for (int mt = 0; mt < MT; ++mt) {
        int rl = wm * (MT * 16) + mt * 16 + quad * 4;
#pragma unroll
        for (int r = 0; r < 4; ++r)
          epf[(rl + r) * 132 + cl] = acc[mt][nt][r] + bv;
      }
    }
    __syncthreads();
    int rr = wave * 2 + (lane >> 5);
    int cc = (lane & 31) * 4;
#pragma unroll
    for (int p = 0; p < R / 8; ++p) {
      int row = p * 8 + rr;
      float4 v = *(const float4*)&epf[row * 132 + cc];
      *(float4*)&outf[(rowA + row) * 1024 + rowB + cc] = v;
    }
  } else if ((int)rowB < 2048) {
    float sc = ((int)rowB < 1024) ? QSCALE : 1.0f;
    u16* ep = smem;
#pragma unroll
    for (int nt = 0; nt < 4; ++nt) {
      int cl = wn * 64 + nt * 16 + qr;
      float bv = bias[rowB + cl];
#pragma unroll
      for (int mt = 0; mt < MT; ++mt) {
        int rl = wm * (MT * 16) + mt * 16 + quad * 4;
#pragma unroll
        for (int r = 0; r < 4; ++r)
          ep[(rl + r) * 136 + cl] = f2bf((acc[mt][nt][r] + bv) * sc);
      }
    }
    __syncthreads();
    int rr = wave * 4 + (lane >> 4);
    int cc = (lane & 15) * 8;
#pragma unroll
    for (int p = 0; p < R / 16; ++p) {
      int row = p * 16 + rr;
      u16x8v v = *(const u16x8v*)&ep[row * 136 + cc];
      *(u16x8v*)&qk[(rowA + row) * 2048 + rowB + cc] = v;
    }
  } else {
    u16* ep = smem;
#pragma unroll
    for (int nt = 0; nt < 4; ++nt) {
      int cl = wn * 64 + nt * 16 + qr;
      float bv = bias[rowB + cl];
#pragma unroll
      for (int mt = 0; mt < MT; ++mt) {
        int rl = wm * (MT * 16) + mt * 16 + quad * 4;
        ushort4 pv;
        pv.x = f2bf(acc[mt][nt][0] + bv);
        pv.y = f2bf(acc[mt][nt][1] + bv);
        pv.z = f2bf(acc[mt][nt][2] + bv);
        pv.w = f2bf(acc[mt][nt][3] + bv);
        *(ushort4*)&ep[cl * 136 + rl] = pv;
      }
    }
    __syncthreads();
    int batch = (int)(rowA >> 11);
    int n_base = (int)(rowA & 2047);
    int rr = wave * 4 + (lane >> 4);
    int cc = (lane & 15) * 8;
#pragma unroll
    for (int p = 0; p < 8; ++p) {
      int d = p * 16 + rr;
      int cglob = (int)rowB - 2048 + d;
      int bh_ = batch * 16 + (cglob >> 6);
      u16x8v v = *(const u16x8v*)&ep[d * 136 + cc];
      *(u16x8v*)&vtout[(size_t)bh_ * 131072 + (size_t)(cglob & 63) * 2048 + n_base + cc] = v;
    }
  }
}

// ------------- flash attention v13: v11 (measured 52.0-52.7) + T5 setprio -----
// v11: 8 waves x 16 q-rows, single-deferred-exp sp-pipeline (QK0+exp0 ->
// QK1(exp deferred) -> PV0 || exp1 -> PV1). r4's setprio test was null on the
// 4-wave LOCKSTEP structure (m190 regime); v11 has 4 waves/SIMD drifting
// through distinct phases between barriers — T5's prerequisite (m218b: +0%
// without phase-split, +21-39% with; m191 +4-7% attn). Wrap the 4 MFMA
// clusters in setprio(1)/(0): zero VGPR/LDS cost, trivially revertable.
__global__ void __launch_bounds__(512, 4) attn_kernel(const u16* __restrict__ qkbuf,
                                                      const u16* __restrict__ vt,
                                                      u16* __restrict__ out) {
  __shared__ alignas(16) u16 kbuf[2][128 * 64];
  __shared__ alignas(16) u16 vbuf[2][64 * 128];
  __shared__ alignas(16) u16 pbuf[8][16 * 64];
  int bh = blockIdx.x;
  int b = bh >> 4, h = bh & 15;
  int m0 = blockIdx.y * 128;
  int tid = threadIdx.x;
  int lane = tid & 63, wave = tid >> 6;  // 8 waves
  int qr = lane & 15, quad = lane >> 4;

  const u16* kbase = qkbuf + (size_t)(b * SEQ) * 2048 + 1024 + h * 64;
  const u16* vtbase = vt + (size_t)bh * 64 * SEQ;
  u16* pw = &pbuf[wave][0];

  int klr = lane >> 3;
  int kcs = (lane & 7) ^ klr;

  const u16* qbase = qkbuf + (size_t)(b * SEQ + m0 + wave * 16) * 2048 + h * 64;
  bf16x8 qf[2];
#pragma unroll
  for (int ks = 0; ks < 2; ++ks)
    qf[ks] = *(const bf16x8*)&qbase[(size_t)qr * 2048 + ks * 32 + quad * 8];

  const bf16x8 vone = __builtin_bit_cast(bf16x8, (u16x8v)((u16)0x3F80));

  f32x4 o[4], l5;
  l5 = (f32x4){0.f, 0.f, 0.f, 0.f};
#pragma unroll
  for (int dt = 0; dt < 4; ++dt) o[dt] = (f32x4){0.f, 0.f, 0.f, 0.f};

  auto stage = [&](int buf, int n0) {
#pragma unroll
    for (int i = 0; i < 2; ++i) {
      int kr = wave * 16 + i * 8 + klr;
      ASYNC16(kbase + (size_t)(n0 + kr) * 2048 + kcs * 8,
              &kbuf[buf][(wave * 16 + i * 8) * 64 + lane * 8]);
    }
#pragma unroll
    for (int i = 0; i < 2; ++i) {
      int vr = wave * 8 + i * 4 + (lane >> 4);
      int vcs = ((lane & 7) ^ (vr & 7)) | (lane & 8);
      ASYNC16(vtbase + (size_t)vr * 2048 + n0 + vcs * 8,
              &vbuf[buf][(wave * 8 + i * 4) * 128 + lane * 8]);
    }
  };

  stage(0, 0);

  for (int t = 0; t < 16; ++t) {
    int cur = t & 1;
    __syncthreads();

    if (t + 1 < 16) stage(cur ^ 1, (t + 1) * 128);

    const u16* kb0 = &kbuf[cur][0];
    const u16* kb1 = &kbuf[cur][64 * 64];
    const u16* vb = &vbuf[cur][0];

    // ---- sp0: QK + exp + pack -> P0 ----
    {
      bf16x8 kf[4][2];
#pragma unroll
      for (int nt = 0; nt < 4; ++nt)
#pragma unroll
        for (int ks = 0; ks < 2; ++ks)
          kf[nt][ks] =
              *(const bf16x8*)&kb0[(nt * 16 + qr) * 64 + (((ks * 4 + quad) ^ (qr & 7)) << 3)];
#pragma unroll
      for (int nt = 0; nt < 4; ++nt) {
        f32x4 z = (f32x4){0.f, 0.f, 0.f, 0.f};
        __builtin_amdgcn_s_setprio(1);
        z = MFMA16(kf[nt][0], qf[0], z);
        z = MFMA16(kf[nt][1], qf[1], z);
        __builtin_amdgcn_s_setprio(0);
        float p0 = __builtin_amdgcn_exp2f(z[0]);
        float p1 = __builtin_amdgcn_exp2f(z[1]);
        float p2 = __builtin_amdgcn_exp2f(z[2]);
        float p3 = __builtin_amdgcn_exp2f(z[3]);
        uint2 pk;
        pk.x = cvt2(p0, p1);
        pk.y = cvt2(p2, p3);
        int nb = nt * 16 + quad * 4;
        int addr = qr * 64 + ((((nb >> 3) ^ (qr & 7)) << 3) | (nb & 7));
        *(uint2*)&pw[addr] = pk;
      }
    }

    // ---- read pf0 (completes before P1 write; wave-private in-order LDS) + vf0 ----
    bf16x8 pf0[2];
#pragma unroll
    for (int ks = 0; ks < 2; ++ks)
      pf0[ks] = *(const bf16x8*)&pw[qr * 64 + (((ks * 4 + quad) ^ (qr & 7)) << 3)];

    bf16x8 vf0[4][2];
#pragma unroll
    for (int dt = 0; dt < 4; ++dt)
#pragma unroll
      for (int ks = 0; ks < 2; ++ks)
        vf0[dt][ks] = *(const bf16x8*)&vb[(dt * 16 + qr) * 128 +
                                          ((((ks * 4 + quad) ^ (qr & 7))) << 3)];

    // ---- sp1 QK: MFMAs now, exp deferred (z1 in 16 VGPRs) ----
    f32x4 z1[4];
    {
      bf16x8 kg[4][2];
#pragma unroll
      for (int nt = 0; nt < 4; ++nt)
#pragma unroll
        for (int ks = 0; ks < 2; ++ks)
          kg[nt][ks] =
              *(const bf16x8*)&kb1[(nt * 16 + qr) * 64 + (((ks * 4 + quad) ^ (qr & 7)) << 3)];
      __builtin_amdgcn_s_setprio(1);
#pragma unroll
      for (int nt = 0; nt < 4; ++nt) {
        f32x4 z = (f32x4){0.f, 0.f, 0.f, 0.f};
        z = MFMA16(kg[nt][0], qf[0], z);
        z1[nt] = MFMA16(kg[nt][1], qf[1], z);
      }
      __builtin_amdgcn_s_setprio(0);
    }

    // ---- PV0 (independent of z1): fills MFMA pipe while exp1 inputs settle ----
    __builtin_amdgcn_s_setprio(1);
#pragma unroll
    for (int dt = 0; dt < 4; ++dt) {
      o[dt] = MFMA16(pf0[0], vf0[dt][0], o[dt]);
      o[dt] = MFMA16(pf0[1], vf0[dt][1], o[dt]);
    }
    l5 = MFMA16(pf0[0], vone, l5);
    l5 = MFMA16(pf0[1], vone, l5);
    __builtin_amdgcn_s_setprio(0);

    // ---- exp1 + pack -> P1 (VALU; overlaps PV0 drain) ----
#pragma unroll
    for (int nt = 0; nt < 4; ++nt) {
      f32x4 z = z1[nt];
      float p0 = __builtin_amdgcn_exp2f(z[0]);
      float p1 = __builtin_amdgcn_exp2f(z[1]);
      float p2 = __builtin_amdgcn_exp2f(z[2]);
      float p3 = __builtin_amdgcn_exp2f(z[3]);
      uint2 pk;
      pk.x = cvt2(p0, p1);
      pk.y = cvt2(p2, p3);
      int nb = nt * 16 + quad * 4;
      int addr = qr * 64 + ((((nb >> 3) ^ (qr & 7)) << 3) | (nb & 7));
      *(uint2*)&pw[addr] = pk;
    }

    // ---- pf1 + vf1, then PV1 ----
    bf16x8 pf1[2];
#pragma unroll
    for (int ks = 0; ks < 2; ++ks)
      pf1[ks] = *(const bf16x8*)&pw[qr * 64 + (((ks * 4 + quad) ^ (qr & 7)) << 3)];

    bf16x8 vf1[4][2];
#pragma unroll
    for (int dt = 0; dt < 4; ++dt)
#pragma unroll
      for (int ks = 0; ks < 2; ++ks)
        vf1[dt][ks] = *(const bf16x8*)&vb[(dt * 16 + qr) * 128 +
                                          ((8 + (((ks * 4 + quad) ^ (qr & 7)))) << 3)];

    __builtin_amdgcn_s_setprio(1);
#pragma unroll
    for (int dt = 0; dt < 4; ++dt) {
      o[dt] = MFMA16(pf1[0], vf1[dt][0], o[dt]);
      o[dt] = MFMA16(pf1[1], vf1[dt][1], o[dt]);
    }
    l5 = MFMA16(pf1[0], vone, l5);
    l5 = MFMA16(pf1[1], vone, l5);
    __builtin_amdgcn_s_setprio(0);
  }

  u16* obase = out + (size_t)(b * SEQ + m0 + wave * 16) * CH + h * 64;
#pragma unroll
  for (int r = 0; r < 4; ++r) {
    float inv = 1.0f / l5[r];
#pragma unroll
    for (int dt = 0; dt < 4; ++dt)
      obase[(size_t)(quad * 4 + r) * CH + dt * 16 + qr] = f2bf(o[dt][r] * inv);
  }
}

extern "C" void kernel_launch(void* const* d_in, const int* in_sizes, int n_in,
                              void* d_out, int out_size, void* d_ws, size_t ws_size,
                              hipStream_t stream) {
  const float* x      = (const float*)d_in[0];
  const float* qkv_w  = (const float*)d_in[1];
  const float* qkv_b  = (const float*)d_in[2];
  const float* proj_w = (const float*)d_in[3];
  const float* proj_b = (const float*)d_in[4];
  float* out = (float*)d_out;

  char* w = (char*)d_ws;
  // ws layout (42 MB):
  //   qkqk  : 4096x2048 bf16 (Q scaled | K, stride 2048) = 16777216 B
  //   xb    : 4096x1024 bf16 = 8388608 B (reused as attn_bf after gemm1)
  //   wprojt: 1024x1024 bf16 = 2097152 B
  //   wqkvt : 3072x1024 bf16 = 6291456 B
  //   vt    : (B*H)x64x2048 bf16 = 8388608 B (written directly by gemm1 epilogue)
  u16* qkqk   = (u16*)w;
  u16* xb     = (u16*)(w + 16777216);
  u16* wprojt = (u16*)(w + 25165824);
  u16* wqkvt  = (u16*)(w + 27262976);
  u16* vt     = (u16*)(w + 33554432);
  u16* attn_bf = xb;

  prep_kernel<<<5120, 256, 0, stream>>>(x, qkv_w, proj_w, xb, wqkvt, wprojt);
  // qkv = x @ qkv_w + b; Q scaled; QK -> qkqk (stride 2048), V -> vt (transposed)
  gemm_kernel<4><<<dim3(24, 32), 256, 0, stream>>>(xb, wqkvt, qkv_b, qkqk, vt, nullptr, 1024, 0);
  attn_kernel<<<dim3(32, 16), 512, 0, stream>>>(qkqk, vt, attn_bf);
  // out = attn @ proj_w + b (fp32); MT=2 at (8,64)
  gemm_kernel<2><<<dim3(8, 64), 256, 0, stream>>>(attn_bf, wprojt, proj_b, nullptr, nullptr, out, 1024, 1);
}

// Round 14
// 175.772 us; speedup vs baseline: 1.0585x; 1.0225x over previous
//
#include <hip/hip_runtime.h>
#include <cstdint>
#include <cstddef>

typedef __bf16 bf16x8 __attribute__((ext_vector_type(8)));
typedef __bf16 bf16x2v __attribute__((ext_vector_type(2)));
typedef unsigned short u16;
typedef u16 u16x8v __attribute__((ext_vector_type(8)));
typedef float  f32x4  __attribute__((ext_vector_type(4)));
typedef unsigned int u32;

#define MFMA16(a, b, c) __builtin_amdgcn_mfma_f32_16x16x32_bf16((a), (b), (c), 0, 0, 0)
#define ASYNC16(g, l)                                                              \
  __builtin_amdgcn_global_load_lds(                                                \
      (const __attribute__((address_space(1))) unsigned int*)(g),                  \
      (__attribute__((address_space(3))) unsigned int*)(l), 16, 0, 0)

__device__ __forceinline__ u16 f2bf(float f) {
  unsigned u = __builtin_bit_cast(unsigned, f);
  u += 0x7fffu + ((u >> 16) & 1u);
  return (u16)(u >> 16);
}

// packed fp32x2 -> bf16x2 (RNE) via hardware cvt
__device__ __forceinline__ u32 cvt2(float a, float b) {
  bf16x2v t;
  t[0] = (__bf16)a;
  t[1] = (__bf16)b;
  return __builtin_bit_cast(u32, t);
}

#define SEQ 2048
#define CH  1024
#define NH  16
#define HD  64
// log2(e) / sqrt(64) folded into stored Q so softmax uses exp2
#define QSCALE 0.18033688011112042f

// ------------- fused prep: cast x + transpose-cast qkv_w + proj_w -------------
// (round-2 original, measured-best)
__global__ void __launch_bounds__(256) prep_kernel(const float* __restrict__ x,
                                                   const float* __restrict__ qkv_w,
                                                   const float* __restrict__ proj_w,
                                                   u16* __restrict__ xb,
                                                   u16* __restrict__ wqkvt,
                                                   u16* __restrict__ wprojt) {
  __shared__ u16 t[64][68];
  int bx = blockIdx.x;
  int tx = threadIdx.x;
  if (bx < 4096) {
    int i = bx * 256 + tx;
    float4 v = ((const float4*)x)[i];
    ushort4 o;
    o.x = f2bf(v.x); o.y = f2bf(v.y); o.z = f2bf(v.z); o.w = f2bf(v.w);
    ((ushort4*)xb)[i] = o;
    return;
  }
  const float* in; u16* out; int R, C, c0, r0;
  if (bx < 4096 + 768) {
    int i = bx - 4096;
    in = qkv_w; out = wqkvt; R = 1024; C = 3072;
    c0 = (i % 48) * 64; r0 = (i / 48) * 64;
  } else {
    int i = bx - 4864;
    in = proj_w; out = wprojt; R = 1024; C = 1024;
    c0 = (i % 16) * 64; r0 = (i / 16) * 64;
  }
  int rr = tx >> 6, cc = tx & 63;
#pragma unroll
  for (int i = 0; i < 16; ++i) {
    int r = i * 4 + rr;
    t[r][cc] = f2bf(in[(size_t)(r0 + r) * C + c0 + cc]);
  }
  __syncthreads();
#pragma unroll
  for (int i = 0; i < 16; ++i) {
    int r = i * 4 + rr;
    out[(size_t)(c0 + r) * R + r0 + cc] = t[cc][r];
  }
}

// ------------- GEMM v4 (round-2 exact, measured-best): BK=64, XOR-swizzled LDS,
//               double-buffered staging, two barriers/iter, coalesced epilogue ----
// Session lessons: XCD swizzle regresses (r3); single-barrier +3us (r4);
// 256²/8-phase neutral (r8); gemm2 MT=4 at (8,32) within noise (r10/r11 —
// non-attn run noise is ±5us, sub-5us GEMM deltas unreadable here).
// CLOSED: MT=4 gemm1 (24,32), MT=2 gemm2 (8,64).
template <int MT>
__global__ void __launch_bounds__(256) gemm_kernel(const u16* __restrict__ A,
                                                   const u16* __restrict__ Bt,
                                                   const float* __restrict__ bias,
                                                   u16* __restrict__ qk,
                                                   u16* __restrict__ vtout,
                                                   float* __restrict__ outf,
                                                   int K, int mode) {
  constexpr int R = MT * 32;
  __shared__ alignas(16) u16 smem[2 * R * 64 + 2 * 128 * 64];
  auto As = (u16(*)[R * 64])smem;
  auto Bs = (u16(*)[128 * 64])(smem + 2 * R * 64);
  int tid = threadIdx.x;
  int lane = tid & 63, wave = tid >> 6;
  int wm = wave >> 1, wn = wave & 1;
  int qr = lane & 15, quad = lane >> 4;
  size_t rowA = (size_t)blockIdx.y * R;
  size_t rowB = (size_t)blockIdx.x * 128;

  int klr = lane >> 3;
  int kcs = (lane & 7) ^ klr;

  f32x4 acc[MT][4];
#pragma unroll
  for (int mt = 0; mt < MT; ++mt)
#pragma unroll
    for (int nt = 0; nt < 4; ++nt) acc[mt][nt] = (f32x4){0.f, 0.f, 0.f, 0.f};

  auto stage = [&](int buf, int k0) {
#pragma unroll
    for (int i = 0; i < R / 32; ++i) {
      int ar = wave * (R / 4) + i * 8;
      ASYNC16(A + (rowA + ar + klr) * K + k0 + kcs * 8, &As[buf][ar * 64 + lane * 8]);
    }
#pragma unroll
    for (int i = 0; i < 4; ++i) {
      int br = wave * 32 + i * 8;
      ASYNC16(Bt + (rowB + br + klr) * K + k0 + kcs * 8, &Bs[buf][br * 64 + lane * 8]);
    }
  };

  stage(0, 0);
  int iters = K >> 6;
  for (int t = 0; t < iters; ++t) {
    int cur = t & 1;
    __syncthreads();
    if (t + 1 < iters) stage(cur ^ 1, (t + 1) * 64);
#pragma unroll
    for (int ks = 0; ks < 2; ++ks) {
      bf16x8 af[MT], bfr[4];
#pragma unroll
      for (int mt = 0; mt < MT; ++mt) {
        int row = wm * (MT * 16) + mt * 16 + qr;
        af[mt] = *(const bf16x8*)&As[cur][row * 64 + (((ks * 4 + quad) ^ (qr & 7)) << 3)];
      }
#pragma unroll
      for (int nt = 0; nt < 4; ++nt) {
        int row = wn * 64 + nt * 16 + qr;
        bfr[nt] = *(const bf16x8*)&Bs[cur][row * 64 + (((ks * 4 + quad) ^ (qr & 7)) << 3)];
      }
#pragma unroll
      for (int mt = 0; mt < MT; ++mt)
#pragma unroll
        for (int nt = 0; nt < 4; ++nt)
          acc[mt][nt] = MFMA16(af[mt], bfr[nt], acc[mt][nt]);
    }
    __syncthreads();
  }

  __syncthreads();

  if (mode == 1) {
    float* epf = (float*)smem;
#pragma unroll
    for (int nt = 0; nt < 4; ++nt) {
      int cl = wn * 64 + nt * 16 + qr;
      float bv = bias[rowB + cl];
#pragma unroll
      for (int mt = 0; mt < MT; ++mt) {
        int rl = wm * (MT * 16) + mt * 16 + quad * 4;
#pragma unroll
        for (int r = 0; r < 4; ++r)
          epf[(rl + r) * 132 + cl] = acc[mt][nt][r] + bv;
      }
    }
    __syncthreads();
    int rr = wave * 2 + (lane >> 5);
    int cc = (lane & 31) * 4;
#pragma unroll
    for (int p = 0; p < R / 8; ++p) {
      int row = p * 8 + rr;
      float4 v = *(const float4*)&epf[row * 132 + cc];
      *(float4*)&outf[(rowA + row) * 1024 + rowB + cc] = v;
    }
  } else if ((int)rowB < 2048) {
    float sc = ((int)rowB < 1024) ? QSCALE : 1.0f;
    u16* ep = smem;
#pragma unroll
    for (int nt = 0; nt < 4; ++nt) {
      int cl = wn * 64 + nt * 16 + qr;
      float bv = bias[rowB + cl];
#pragma unroll
      for (int mt = 0; mt < MT; ++mt) {
        int rl = wm * (MT * 16) + mt * 16 + quad * 4;
#pragma unroll
        for (int r = 0; r < 4; ++r)
          ep[(rl + r) * 136 + cl] = f2bf((acc[mt][nt][r] + bv) * sc);
      }
    }
    __syncthreads();
    int rr = wave * 4 + (lane >> 4);
    int cc = (lane & 15) * 8;
#pragma unroll
    for (int p = 0; p < R / 16; ++p) {
      int row = p * 16 + rr;
      u16x8v v = *(const u16x8v*)&ep[row * 136 + cc];
      *(u16x8v*)&qk[(rowA + row) * 2048 + rowB + cc] = v;
    }
  } else {
    u16* ep = smem;
#pragma unroll
    for (int nt = 0; nt < 4; ++nt) {
      int cl = wn * 64 + nt * 16 + qr;
      float bv = bias[rowB + cl];
#pragma unroll
      for (int mt = 0; mt < MT; ++mt) {
        int rl = wm * (MT * 16) + mt * 16 + quad * 4;
        ushort4 pv;
        pv.x = f2bf(acc[mt][nt][0] + bv);
        pv.y = f2bf(acc[mt][nt][1] + bv);
        pv.z = f2bf(acc[mt][nt][2] + bv);
        pv.w = f2bf(acc[mt][nt][3] + bv);
        *(ushort4*)&ep[cl * 136 + rl] = pv;
      }
    }
    __syncthreads();
    int batch = (int)(rowA >> 11);
    int n_base = (int)(rowA & 2047);
    int rr = wave * 4 + (lane >> 4);
    int cc = (lane & 15) * 8;
#pragma unroll
    for (int p = 0; p < 8; ++p) {
      int d = p * 16 + rr;
      int cglob = (int)rowB - 2048 + d;
      int bh_ = batch * 16 + (cglob >> 6);
      u16x8v v = *(const u16x8v*)&ep[d * 136 + cc];
      *(u16x8v*)&vtout[(size_t)bh_ * 131072 + (size_t)(cglob & 63) * 2048 + n_base + cc] = v;
    }
  }
}

// ------------- flash attention v11 (session-best attn, 52.0-52.8us) -----------
// 8 waves x 16 q-rows (occ ~34%, VGPR 64) + single-deferred-exp sp-pipeline:
// QK0+exp0 -> QK1 (exp deferred, z1 in regs) -> PV0 (MFMA, overlaps exp1's
// VALU) -> exp1 -> PV1. Closed variants (all measured worse): v12 double-defer
// +1.6us (serializes MFMA pipe); v13 setprio +6.2us (waves resync at per-tile
// barriers -> m190 lockstep-hurt regime, NOT m191's desynced regime); 4-wave
// forms 56.5+; no-staging 125 (staging IS the prefetch pipeline).
__global__ void __launch_bounds__(512, 4) attn_kernel(const u16* __restrict__ qkbuf,
                                                      const u16* __restrict__ vt,
                                                      u16* __restrict__ out) {
  __shared__ alignas(16) u16 kbuf[2][128 * 64];
  __shared__ alignas(16) u16 vbuf[2][64 * 128];
  __shared__ alignas(16) u16 pbuf[8][16 * 64];
  int bh = blockIdx.x;
  int b = bh >> 4, h = bh & 15;
  int m0 = blockIdx.y * 128;
  int tid = threadIdx.x;
  int lane = tid & 63, wave = tid >> 6;  // 8 waves
  int qr = lane & 15, quad = lane >> 4;

  const u16* kbase = qkbuf + (size_t)(b * SEQ) * 2048 + 1024 + h * 64;
  const u16* vtbase = vt + (size_t)bh * 64 * SEQ;
  u16* pw = &pbuf[wave][0];

  int klr = lane >> 3;
  int kcs = (lane & 7) ^ klr;

  const u16* qbase = qkbuf + (size_t)(b * SEQ + m0 + wave * 16) * 2048 + h * 64;
  bf16x8 qf[2];
#pragma unroll
  for (int ks = 0; ks < 2; ++ks)
    qf[ks] = *(const bf16x8*)&qbase[(size_t)qr * 2048 + ks * 32 + quad * 8];

  const bf16x8 vone = __builtin_bit_cast(bf16x8, (u16x8v)((u16)0x3F80));

  f32x4 o[4], l5;
  l5 = (f32x4){0.f, 0.f, 0.f, 0.f};
#pragma unroll
  for (int dt = 0; dt < 4; ++dt) o[dt] = (f32x4){0.f, 0.f, 0.f, 0.f};

  auto stage = [&](int buf, int n0) {
#pragma unroll
    for (int i = 0; i < 2; ++i) {
      int kr = wave * 16 + i * 8 + klr;
      ASYNC16(kbase + (size_t)(n0 + kr) * 2048 + kcs * 8,
              &kbuf[buf][(wave * 16 + i * 8) * 64 + lane * 8]);
    }
#pragma unroll
    for (int i = 0; i < 2; ++i) {
      int vr = wave * 8 + i * 4 + (lane >> 4);
      int vcs = ((lane & 7) ^ (vr & 7)) | (lane & 8);
      ASYNC16(vtbase + (size_t)vr * 2048 + n0 + vcs * 8,
              &vbuf[buf][(wave * 8 + i * 4) * 128 + lane * 8]);
    }
  };

  stage(0, 0);

  for (int t = 0; t < 16; ++t) {
    int cur = t & 1;
    __syncthreads();

    if (t + 1 < 16) stage(cur ^ 1, (t + 1) * 128);

    const u16* kb0 = &kbuf[cur][0];
    const u16* kb1 = &kbuf[cur][64 * 64];
    const u16* vb = &vbuf[cur][0];

    // ---- sp0: QK + exp + pack -> P0 ----
    {
      bf16x8 kf[4][2];
#pragma unroll
      for (int nt = 0; nt < 4; ++nt)
#pragma unroll
        for (int ks = 0; ks < 2; ++ks)
          kf[nt][ks] =
              *(const bf16x8*)&kb0[(nt * 16 + qr) * 64 + (((ks * 4 + quad) ^ (qr & 7)) << 3)];
#pragma unroll
      for (int nt = 0; nt < 4; ++nt) {
        f32x4 z = (f32x4){0.f, 0.f, 0.f, 0.f};
        z = MFMA16(kf[nt][0], qf[0], z);
        z = MFMA16(kf[nt][1], qf[1], z);
        float p0 = __builtin_amdgcn_exp2f(z[0]);
        float p1 = __builtin_amdgcn_exp2f(z[1]);
        float p2 = __builtin_amdgcn_exp2f(z[2]);
        float p3 = __builtin_amdgcn_exp2f(z[3]);
        uint2 pk;
        pk.x = cvt2(p0, p1);
        pk.y = cvt2(p2, p3);
        int nb = nt * 16 + quad * 4;
        int addr = qr * 64 + ((((nb >> 3) ^ (qr & 7)) << 3) | (nb & 7));
        *(uint2*)&pw[addr] = pk;
      }
    }

    // ---- read pf0 (completes before P1 write; wave-private in-order LDS) + vf0 ----
    bf16x8 pf0[2];
#pragma unroll
    for (int ks = 0; ks < 2; ++ks)
      pf0[ks] = *(const bf16x8*)&pw[qr * 64 + (((ks * 4 + quad) ^ (qr & 7)) << 3)];

    bf16x8 vf0[4][2];
#pragma unroll
    for (int dt = 0; dt < 4; ++dt)
#pragma unroll
      for (int ks = 0; ks < 2; ++ks)
        vf0[dt][ks] = *(const bf16x8*)&vb[(dt * 16 + qr) * 128 +
                                          ((((ks * 4 + quad) ^ (qr & 7))) << 3)];

    // ---- sp1 QK: MFMAs now, exp deferred (z1 in 16 VGPRs) ----
    f32x4 z1[4];
    {
      bf16x8 kg[4][2];
#pragma unroll
      for (int nt = 0; nt < 4; ++nt)
#pragma unroll
        for (int ks = 0; ks < 2; ++ks)
          kg[nt][ks] =
              *(const bf16x8*)&kb1[(nt * 16 + qr) * 64 + (((ks * 4 + quad) ^ (qr & 7)) << 3)];
#pragma unroll
      for (int nt = 0; nt < 4; ++nt) {
        f32x4 z = (f32x4){0.f, 0.f, 0.f, 0.f};
        z = MFMA16(kg[nt][0], qf[0], z);
        z1[nt] = MFMA16(kg[nt][1], qf[1], z);
      }
    }

    // ---- PV0 (independent of z1): fills MFMA pipe while exp1 inputs settle ----
#pragma unroll
    for (int dt = 0; dt < 4; ++dt) {
      o[dt] = MFMA16(pf0[0], vf0[dt][0], o[dt]);
      o[dt] = MFMA16(pf0[1], vf0[dt][1], o[dt]);
    }
    l5 = MFMA16(pf0[0], vone, l5);
    l5 = MFMA16(pf0[1], vone, l5);

    // ---- exp1 + pack -> P1 (VALU; overlaps PV0 drain) ----
#pragma unroll
    for (int nt = 0; nt < 4; ++nt) {
      f32x4 z = z1[nt];
      float p0 = __builtin_amdgcn_exp2f(z[0]);
      float p1 = __builtin_amdgcn_exp2f(z[1]);
      float p2 = __builtin_amdgcn_exp2f(z[2]);
      float p3 = __builtin_amdgcn_exp2f(z[3]);
      uint2 pk;
      pk.x = cvt2(p0, p1);
      pk.y = cvt2(p2, p3);
      int nb = nt * 16 + quad * 4;
      int addr = qr * 64 + ((((nb >> 3) ^ (qr & 7)) << 3) | (nb & 7));
      *(uint2*)&pw[addr] = pk;
    }

    // ---- pf1 + vf1, then PV1 ----
    bf16x8 pf1[2];
#pragma unroll
    for (int ks = 0; ks < 2; ++ks)
      pf1[ks] = *(const bf16x8*)&pw[qr * 64 + (((ks * 4 + quad) ^ (qr & 7)) << 3)];

    bf16x8 vf1[4][2];
#pragma unroll
    for (int dt = 0; dt < 4; ++dt)
#pragma unroll
      for (int ks = 0; ks < 2; ++ks)
        vf1[dt][ks] = *(const bf16x8*)&vb[(dt * 16 + qr) * 128 +
                                          ((8 + (((ks * 4 + quad) ^ (qr & 7)))) << 3)];

#pragma unroll
    for (int dt = 0; dt < 4; ++dt) {
      o[dt] = MFMA16(pf1[0], vf1[dt][0], o[dt]);
      o[dt] = MFMA16(pf1[1], vf1[dt][1], o[dt]);
    }
    l5 = MFMA16(pf1[0], vone, l5);
    l5 = MFMA16(pf1[1], vone, l5);
  }

  u16* obase = out + (size_t)(b * SEQ + m0 + wave * 16) * CH + h * 64;
#pragma unroll
  for (int r = 0; r < 4; ++r) {
    float inv = 1.0f / l5[r];
#pragma unroll
    for (int dt = 0; dt < 4; ++dt)
      obase[(size_t)(quad * 4 + r) * CH + dt * 16 + qr] = f2bf(o[dt][r] * inv);
  }
}

extern "C" void kernel_launch(void* const* d_in, const int* in_sizes, int n_in,
                              void* d_out, int out_size, void* d_ws, size_t ws_size,
                              hipStream_t stream) {
  const float* x      = (const float*)d_in[0];
  const float* qkv_w  = (const float*)d_in[1];
  const float* qkv_b  = (const float*)d_in[2];
  const float* proj_w = (const float*)d_in[3];
  const float* proj_b = (const float*)d_in[4];
  float* out = (float*)d_out;

  char* w = (char*)d_ws;
  // ws layout (42 MB):
  //   qkqk  : 4096x2048 bf16 (Q scaled | K, stride 2048) = 16777216 B
  //   xb    : 4096x1024 bf16 = 8388608 B (reused as attn_bf after gemm1)
  //   wprojt: 1024x1024 bf16 = 2097152 B
  //   wqkvt : 3072x1024 bf16 = 6291456 B
  //   vt    : (B*H)x64x2048 bf16 = 8388608 B (written directly by gemm1 epilogue)
  u16* qkqk   = (u16*)w;
  u16* xb     = (u16*)(w + 16777216);
  u16* wprojt = (u16*)(w + 25165824);
  u16* wqkvt  = (u16*)(w + 27262976);
  u16* vt     = (u16*)(w + 33554432);
  u16* attn_bf = xb;

  prep_kernel<<<5120, 256, 0, stream>>>(x, qkv_w, proj_w, xb, wqkvt, wprojt);
  // qkv = x @ qkv_w + b; Q scaled; QK -> qkqk (stride 2048), V -> vt (transposed)
  gemm_kernel<4><<<dim3(24, 32), 256, 0, stream>>>(xb, wqkvt, qkv_b, qkqk, vt, nullptr, 1024, 0);
  attn_kernel<<<dim3(32, 16), 512, 0, stream>>>(qkqk, vt, attn_bf);
  // out = attn @ proj_w + b (fp32); MT=2 at (8,64)
  gemm_kernel<2><<<dim3(8, 64), 256, 0, stream>>>(attn_bf, wprojt, proj_b, nullptr, nullptr, out, 1024, 1);
}